// Round 3
// baseline (366.722 us; speedup 1.0000x reference)
//
#include <hip/hip_runtime.h>
#include <hip/hip_bf16.h>

typedef short  bf16x8 __attribute__((ext_vector_type(8)));
typedef float  f32x16 __attribute__((ext_vector_type(16)));
typedef float  f32x4v __attribute__((ext_vector_type(4)));

#define D  128
#define CH 32   // edges per wave-chunk (one 32-row MFMA M-tile)

// f32 -> bf16 round-to-nearest-even (finite inputs)
__device__ __forceinline__ short f2bf(float f) {
    unsigned u = __float_as_uint(f);
    u = (u + 0x7fffu + ((u >> 16) & 1u)) >> 16;
    return (short)u;
}

// Per-row XOR mask for W1^T LDS rows (256 B stride): spreads the 32-lane
// column-slice ds_read_b128 across bank groups (G4 / T2 family).
__device__ __forceinline__ int wmask(int row) {
    return ((row & 7) << 4) ^ ((row & 8) << 2);
}

// LDS = 32 KB (W1^T only) -> 4 blocks/CU at launch_bounds(256,4) = 16 waves/CU
__global__ __launch_bounds__(256, 4)
void edge_decoder_kernel(const float* __restrict__ left,
                         const float* __restrict__ right,
                         const int* __restrict__ pairs,
                         const float* __restrict__ W1,
                         const float* __restrict__ b1,
                         const float* __restrict__ W2,
                         const float* __restrict__ b2,
                         float* __restrict__ out, int E)
{
    __shared__ char w1t[32768];          // W1^T bf16 [col][k], swizzled

    const int tid  = threadIdx.x;
    const int lane = tid & 63;
    const int wid  = tid >> 6;
    const int e32  = lane & 31;          // edge slot (A row) / hidden col slot
    const int hi   = lane >> 5;          // k-half selector

    // ---- Phase 0: W1^T (bf16, transposed, swizzled) into LDS ----
    #pragma unroll 4
    for (int j = 0; j < 64; ++j) {
        int idx = j * 256 + tid;         // coalesced read of W1[k][c]
        int k = idx >> 7, c = idx & 127;
        *(short*)(w1t + (c << 8) + ((2 * k) ^ wmask(c))) = f2bf(W1[idx]);
    }

    // per-lane slices of b1 / W2 (hidden unit n = ct*32 + e32 matches C cols)
    float b1v[4], w2v[4];
    #pragma unroll
    for (int ct = 0; ct < 4; ++ct) {
        b1v[ct] = b1[ct * 32 + e32];
        w2v[ct] = W2[ct * 32 + e32];
    }
    const float b2s = b2[0];

    __syncthreads();                     // W1^T ready (only barrier)

    const int chunks = (E + CH - 1) / CH;
    const int stride = gridDim.x * 4;    // chunk-stride in wave units

    int c = blockIdx.x * 4 + wid;
    if (c >= chunks) return;

    // each lane loads ITS edge's indices directly — no shuffles
    auto ldidx = [&](int cc, const int* p) {
        int e0 = cc * CH + e32;
        if (e0 >= E) e0 = E - 1;         // tail clamp: safe gather
        return p[e0];
    };

    int i0 = ldidx(c, pairs);
    int i1 = ldidx(c, pairs + E);

    while (true) {
        const int cn = c + stride;
        // prefetch next chunk's indices; hides under gather+MFMA
        int i0n = 0, i1n = 0;
        if (cn < chunks) { i0n = ldidx(cn, pairs); i1n = ldidx(cn, pairs + E); }

        const float* __restrict__ lrow = left  + i0 * D + hi * 8;
        const float* __restrict__ rrow = right + i1 * D + hi * 8;

        f32x16 acc[4];
        #pragma unroll
        for (int ct = 0; ct < 4; ++ct)
            #pragma unroll
            for (int r = 0; r < 16; ++r) acc[ct][r] = 0.f;

        // ---- gather -> A-frag in registers -> MFMA, k-step loop ----
        // A lane-map: row = e32, k = kt*16 + hi*8 + e  (8 k-contiguous / lane)
        // B lane-map: col = e32, same k function -> k-perm invariant.
        #pragma unroll
        for (int kt = 0; kt < 8; ++kt) {
            const f32x4v lv0 = *(const f32x4v*)(lrow + kt * 16);
            const f32x4v lv1 = *(const f32x4v*)(lrow + kt * 16 + 4);
            const f32x4v rv0 = *(const f32x4v*)(rrow + kt * 16);
            const f32x4v rv1 = *(const f32x4v*)(rrow + kt * 16 + 4);

            bf16x8 a;
            #pragma unroll
            for (int e = 0; e < 4; ++e) {
                a[e]     = f2bf(lv0[e] * rv0[e]);
                a[e + 4] = f2bf(lv1[e] * rv1[e]);
            }

            #pragma unroll
            for (int ct = 0; ct < 4; ++ct) {
                const int col = ct * 32 + e32;
                const bf16x8 bfr = *(const bf16x8*)(
                    w1t + (col << 8) + ((kt * 32 + hi * 16) ^ wmask(col)));
                acc[ct] = __builtin_amdgcn_mfma_f32_32x32x16_bf16(
                    a, bfr, acc[ct], 0, 0, 0);
            }
        }

        // ---- bias + ReLU + dot(W2) per edge-row, then 32-lane reduce ----
        // C layout (HW-measured): col = lane&31, row = (reg&3)+8*(reg>>2)+4*hi
        float p[16];
        #pragma unroll
        for (int r = 0; r < 16; ++r) {
            float s = 0.f;
            #pragma unroll
            for (int ct = 0; ct < 4; ++ct) {
                float h = fmaxf(acc[ct][r] + b1v[ct], 0.f);
                s = fmaf(h, w2v[ct], s);
            }
            p[r] = s;
        }
        #pragma unroll
        for (int r = 0; r < 16; ++r) {
            #pragma unroll
            for (int s = 1; s < 32; s <<= 1)
                p[r] += __shfl_xor(p[r], s);   // reduce over 32 cols
        }

        const int base = c * CH;
        #pragma unroll
        for (int r = 0; r < 16; ++r) {         // compile-time reg index
            if (e32 == r) {
                const int row = (r & 3) + 8 * (r >> 2) + 4 * hi;
                const int e = base + row;
                if (e < E) out[e] = 1.f / (1.f + __expf(-(p[r] + b2s)));
            }
        }

        if (cn >= chunks) break;
        c = cn; i0 = i0n; i1 = i1n;
    }
}

extern "C" void kernel_launch(void* const* d_in, const int* in_sizes, int n_in,
                              void* d_out, int out_size, void* d_ws, size_t ws_size,
                              hipStream_t stream) {
    const float* left  = (const float*)d_in[0];
    const float* right = (const float*)d_in[1];
    const int*   pairs = (const int*)d_in[2];
    const float* W1    = (const float*)d_in[3];
    const float* b1    = (const float*)d_in[4];
    const float* W2    = (const float*)d_in[5];
    const float* b2    = (const float*)d_in[6];
    float* out = (float*)d_out;

    const int E = in_sizes[2] / 2;                 // pairs is [2][E]
    const int chunks = (E + CH - 1) / CH;
    int blocks = 1024;                             // 4 blocks/CU * 256 CU
    const int need = (chunks + 3) / 4;             // 4 wave-chunks per block
    if (need < blocks) blocks = need;
    edge_decoder_kernel<<<blocks, 256, 0, stream>>>(
        left, right, pairs, W1, b1, W2, b2, out, E);
}

// Round 5
// 149.207 us; speedup vs baseline: 2.4578x; 2.4578x over previous
//
#include <hip/hip_runtime.h>
#include <hip/hip_bf16.h>

typedef short bf16x8 __attribute__((ext_vector_type(8)));
typedef float f32x4  __attribute__((ext_vector_type(4)));

#define D     128
#define CH    16          // edges per wave-chunk (wave-private staging)
#define WAVES 8           // waves per block
#define BLK   (WAVES*64)  // 512 threads

// f32 -> bf16 round-to-nearest-even (finite inputs)
__device__ __forceinline__ short f2bf(float f) {
    unsigned u = __float_as_uint(f);
    u = (u + 0x7fffu + ((u >> 16) & 1u)) >> 16;
    return (short)u;
}

// LDS byte offset for [row][128 bf16], XOR-swizzled (16B-block granular) to
// kill the stride-256B bank conflict on ds_read_b128 column-slices (G4).
__device__ __forceinline__ int swz(int row, int intra) {
    return (row << 8) + (intra ^ ((row & 7) << 4));
}

// Prep: build the exact swizzled W1^T bf16 LDS image (32 KB) in d_ws, so the
// main kernel's staging is a linear conflict-free coalesced copy (kills the
// 1e7 SQ_LDS_BANK_CONFLICT from r2's 2B scattered staging writes).
__global__ void prep_w1(const float* __restrict__ W1, short* __restrict__ ws) {
    const int idx = blockIdx.x * 256 + threadIdx.x;   // 64 blocks x 256 = 16384
    const int k = idx >> 7, c = idx & 127;            // W1 is [k][c]
    ws[((c << 8) + ((2 * k) ^ ((c & 7) << 4))) >> 1] = f2bf(W1[idx]);
}

// LDS: 32 KB W1^T + 8 waves * 4 KB x-stage = 64 KB static
// -> 2 blocks/CU = 16 waves/CU; VGPR cap 128 at (512,4), kernel uses ~68.
__global__ __launch_bounds__(BLK, 4)
void edge_decoder_kernel(const float* __restrict__ left,
                         const float* __restrict__ right,
                         const int* __restrict__ pairs,
                         const short* __restrict__ w1ws,
                         const float* __restrict__ W1,
                         const float* __restrict__ b1,
                         const float* __restrict__ W2,
                         const float* __restrict__ b2,
                         float* __restrict__ out, int E, int use_ws)
{
    __shared__ char smem[65536];
    char* const w1t = smem;                                     // 32 KB
    char* const xls = smem + 32768 + (threadIdx.x >> 6) * 4096; // wave-private

    const int tid  = threadIdx.x;
    const int lane = tid & 63;
    const int wid  = tid >> 6;
    const int lg   = lane >> 4;       // lanegroup 0..3
    const int lm   = lane & 15;
    const int half = lane >> 5;       // 0: pairs0 / even edges, 1: pairs1 / odd
    const int l32  = lane & 31;

    // ---- Phase 0: W1^T image -> LDS ----
    if (use_ws) {
        // linear coalesced 16B copy, zero bank conflicts
        for (int j = tid; j < 2048; j += BLK)
            *(f32x4*)(w1t + j * 16) = ((const f32x4*)w1ws)[j];
    } else {
        // fallback: in-kernel scatter staging (conflicted but correct)
        for (int j = tid; j < 16384; j += BLK) {
            int k = j >> 7, c = j & 127;
            *(short*)(w1t + swz(c, 2 * k)) = f2bf(W1[j]);
        }
    }

    // per-lane slices of b1 / W2 (col = ct*16 + lm matches C-frag layout)
    float b1v[8], w2v[8];
    #pragma unroll
    for (int ct = 0; ct < 8; ++ct) {
        b1v[ct] = b1[ct * 16 + lm];
        w2v[ct] = W2[ct * 16 + lm];
    }
    const float b2s = b2[0];

    __syncthreads();                          // W1^T ready (only barrier)

    const int chunks = (E + CH - 1) / CH;
    const int stride = gridDim.x * WAVES;     // chunk-stride in wave units

    int c = blockIdx.x * WAVES + wid;
    if (c >= chunks) return;

    // index layout per chunk: lanes 0-15 hold pairs0[base+lm],
    // lanes 32-47 hold pairs1[base+lm] (lanes 16-31/48-63 duplicate).
    auto load_idx = [&](int cc) {
        int e0 = cc * CH + lm;
        if (e0 >= E) e0 = E - 1;              // tail clamp: safe gather
        return pairs[half * E + e0];
    };

    int idxv = load_idx(c);

    while (true) {
        const int cn = c + stride;
        const int base = c * CH;
        // prefetch next chunk's indices; latency hides under MFMA/epilogue
        const int idxv_n = (cn < chunks) ? load_idx(cn) : 0;

        // ---- gather: whole-row reads, ALL 16 issued in one burst (keeps
        // the L2 temporal footprint compact — r3 post-mortem lesson) ----
        float4 lv[8], rv[8];
        #pragma unroll
        for (int j = 0; j < 8; ++j) {
            const int eoff = 2 * j + half;    // 2 edges per j
            const int iL = __shfl(idxv, eoff);
            const int iR = __shfl(idxv, 32 + eoff);
            lv[j] = *(const float4*)(left  + iL * D + l32 * 4);
            rv[j] = *(const float4*)(right + iR * D + l32 * 4);
        }
        // ---- multiply + bf16 + transpose-stage to wave-private LDS ----
        #pragma unroll
        for (int j = 0; j < 8; ++j) {
            const int eoff = 2 * j + half;
            short4 xb;
            xb.x = f2bf(lv[j].x * rv[j].x);
            xb.y = f2bf(lv[j].y * rv[j].y);
            xb.z = f2bf(lv[j].z * rv[j].z);
            xb.w = f2bf(lv[j].w * rv[j].w);
            *(short4*)(xls + swz(eoff, l32 * 8)) = xb;
        }

        // ---- MFMA: A and B share the same k-mapping (K-perm invariant) ----
        bf16x8 afr[4];
        #pragma unroll
        for (int kt = 0; kt < 4; ++kt)
            afr[kt] = *(const bf16x8*)(xls + swz(lm, kt * 64 + lg * 16));

        f32x4 acc[8];
        #pragma unroll
        for (int ct = 0; ct < 8; ++ct) acc[ct] = (f32x4){0.f, 0.f, 0.f, 0.f};

        #pragma unroll
        for (int kt = 0; kt < 4; ++kt)
            #pragma unroll
            for (int ct = 0; ct < 8; ++ct) {
                const bf16x8 bfr = *(const bf16x8*)(
                    w1t + swz(ct * 16 + lm, kt * 64 + lg * 16));
                acc[ct] = __builtin_amdgcn_mfma_f32_16x16x32_bf16(
                    afr[kt], bfr, acc[ct], 0, 0, 0);
            }

        // ---- bias + ReLU + dot(W2) + 16-lane reduce + sigmoid ----
        // C-frag layout (HW-measured): col = lane&15, row = (lane>>4)*4 + reg.
        float p0 = 0.f, p1 = 0.f, p2 = 0.f, p3 = 0.f;
        #pragma unroll
        for (int ct = 0; ct < 8; ++ct) {
            float h0 = fmaxf(acc[ct][0] + b1v[ct], 0.f);
            float h1 = fmaxf(acc[ct][1] + b1v[ct], 0.f);
            float h2 = fmaxf(acc[ct][2] + b1v[ct], 0.f);
            float h3 = fmaxf(acc[ct][3] + b1v[ct], 0.f);
            p0 = fmaf(h0, w2v[ct], p0);
            p1 = fmaf(h1, w2v[ct], p1);
            p2 = fmaf(h2, w2v[ct], p2);
            p3 = fmaf(h3, w2v[ct], p3);
        }
        #pragma unroll
        for (int s = 1; s < 16; s <<= 1) {
            p0 += __shfl_xor(p0, s);
            p1 += __shfl_xor(p1, s);
            p2 += __shfl_xor(p2, s);
            p3 += __shfl_xor(p3, s);
        }
        if (lm < 4) {
            const float pv = (lm & 2) ? ((lm & 1) ? p3 : p2)
                                      : ((lm & 1) ? p1 : p0);
            const int e = base + lg * 4 + lm;   // row = lg*4 + reg
            if (e < E) out[e] = 1.f / (1.f + __expf(-(pv + b2s)));
        }

        if (cn >= chunks) break;
        c = cn;
        idxv = idxv_n;
    }
}

extern "C" void kernel_launch(void* const* d_in, const int* in_sizes, int n_in,
                              void* d_out, int out_size, void* d_ws, size_t ws_size,
                              hipStream_t stream) {
    const float* left  = (const float*)d_in[0];
    const float* right = (const float*)d_in[1];
    const int*   pairs = (const int*)d_in[2];
    const float* W1    = (const float*)d_in[3];
    const float* b1    = (const float*)d_in[4];
    const float* W2    = (const float*)d_in[5];
    const float* b2    = (const float*)d_in[6];
    float* out = (float*)d_out;

    const int E = in_sizes[2] / 2;                 // pairs is [2][E]
    const int chunks = (E + CH - 1) / CH;

    const int use_ws = (ws_size >= 32768) ? 1 : 0;
    if (use_ws)
        prep_w1<<<64, 256, 0, stream>>>(W1, (short*)d_ws);

    int blocks = 512;                              // 2 blocks/CU * 256 CU
    const int need = (chunks + WAVES - 1) / WAVES;
    if (need < blocks) blocks = need;
    edge_decoder_kernel<<<blocks, BLK, 0, stream>>>(
        left, right, pairs, (const short*)d_ws, W1, b1, W2, b2, out, E, use_ws);
}

// Round 6
// 107.002 us; speedup vs baseline: 3.4272x; 1.3944x over previous
//
#include <hip/hip_runtime.h>
#include <hip/hip_bf16.h>

typedef short bf16x8 __attribute__((ext_vector_type(8)));
typedef short short8 __attribute__((ext_vector_type(8)));
typedef float f32x4  __attribute__((ext_vector_type(4)));

#define D     128
#define CH    16          // edges per wave-chunk (wave-private staging)
#define WAVES 8           // waves per block
#define BLK   (WAVES*64)  // 512 threads

// f32 -> bf16 round-to-nearest-even (finite inputs)
__device__ __forceinline__ short f2bf(float f) {
    unsigned u = __float_as_uint(f);
    u = (u + 0x7fffu + ((u >> 16) & 1u)) >> 16;
    return (short)u;
}
__device__ __forceinline__ float bf2f(short s) {
    return __uint_as_float(((unsigned)(unsigned short)s) << 16);
}

// LDS byte offset for [row][128 bf16], XOR-swizzled (16B-block granular) to
// kill the stride-256B bank conflict on ds_read_b128 column-slices (G4).
__device__ __forceinline__ int swz(int row, int intra) {
    return (row << 8) + (intra ^ ((row & 7) << 4));
}

// Prep A: swizzled W1^T bf16 LDS image (32 KB) in d_ws -> main kernel staging
// is a linear conflict-free coalesced copy.
__global__ void prep_w1(const float* __restrict__ W1, short* __restrict__ ws) {
    const int idx = blockIdx.x * 256 + threadIdx.x;   // 64 blocks x 256 = 16384
    const int k = idx >> 7, c = idx & 127;            // W1 is [k][c]
    ws[((c << 8) + ((2 * k) ^ ((c & 7) << 4))) >> 1] = f2bf(W1[idx]);
}

// Prep B: f32 table -> bf16 table (halves the gather miss bytes).
__global__ void conv_bf16(const float* __restrict__ src, short* __restrict__ dst,
                          int n8) {                   // n8 = elements/8
    int i = blockIdx.x * blockDim.x + threadIdx.x;
    const int stride = gridDim.x * blockDim.x;
    for (; i < n8; i += stride) {
        const f32x4 a = ((const f32x4*)src)[2 * i];
        const f32x4 b = ((const f32x4*)src)[2 * i + 1];
        short8 o;
        o[0] = f2bf(a[0]); o[1] = f2bf(a[1]); o[2] = f2bf(a[2]); o[3] = f2bf(a[3]);
        o[4] = f2bf(b[0]); o[5] = f2bf(b[1]); o[6] = f2bf(b[2]); o[7] = f2bf(b[3]);
        ((short8*)dst)[i] = o;
    }
}

// LDS: 32 KB W1^T + 8 waves * 4 KB x-stage = 64 KB static -> 2 blocks/CU.
// MODE 0: f32 tables (fallback). MODE 1: bf16 tables from d_ws.
template <int MODE>
__global__ __launch_bounds__(BLK, 4)
void edge_decoder_kernel(const float* __restrict__ left,
                         const float* __restrict__ right,
                         const short* __restrict__ leftb,
                         const short* __restrict__ rightb,
                         const int* __restrict__ pairs,
                         const short* __restrict__ w1ws,
                         const float* __restrict__ b1,
                         const float* __restrict__ W2,
                         const float* __restrict__ b2,
                         float* __restrict__ out, int E)
{
    __shared__ char smem[65536];
    char* const w1t = smem;                                     // 32 KB
    char* const xls = smem + 32768 + (threadIdx.x >> 6) * 4096; // wave-private

    const int tid  = threadIdx.x;
    const int lane = tid & 63;
    const int wid  = tid >> 6;
    const int lg   = lane >> 4;       // lanegroup 0..3
    const int lm   = lane & 15;
    const int half = lane >> 5;       // 0: pairs0 / even edges, 1: pairs1 / odd
    const int l32  = lane & 31;

    // ---- Phase 0: W1^T image -> LDS (linear coalesced, conflict-free) ----
    for (int j = tid; j < 2048; j += BLK)
        *(f32x4*)(w1t + j * 16) = ((const f32x4*)w1ws)[j];

    // per-lane slices of b1 / W2 (col = ct*16 + lm matches C-frag layout)
    float b1v[8], w2v[8];
    #pragma unroll
    for (int ct = 0; ct < 8; ++ct) {
        b1v[ct] = b1[ct * 16 + lm];
        w2v[ct] = W2[ct * 16 + lm];
    }
    const float b2s = b2[0];

    __syncthreads();                          // W1^T ready (only barrier)

    const int chunks = (E + CH - 1) / CH;
    const int stride = gridDim.x * WAVES;     // chunk-stride in wave units

    int c = blockIdx.x * WAVES + wid;
    if (c >= chunks) return;

    // index layout per chunk: lanes 0-15 hold pairs0[base+lm],
    // lanes 32-47 hold pairs1[base+lm] (lanes 16-31/48-63 duplicate).
    auto load_idx = [&](int cc) {
        int e0 = cc * CH + lm;
        if (e0 >= E) e0 = E - 1;              // tail clamp: safe gather
        return pairs[half * E + e0];
    };

    int idxv = load_idx(c);

    while (true) {
        const int cn = c + stride;
        const int base = c * CH;
        // prefetch next chunk's indices; latency hides under MFMA/epilogue
        const int idxv_n = (cn < chunks) ? load_idx(cn) : 0;

        if (MODE == 1) {
            // ---- bf16 gather: 16B/lane, 16 lanes/row -> 4 whole rows per
            // instruction, 8 instructions per chunk, tight burst ----
            const int q  = lane >> 4;         // quarter 0..3 -> edge 4j+q
            const int lq = lane & 15;         // channels [8*lq, 8*lq+8)
            short8 lv[4], rv[4];
            #pragma unroll
            for (int j = 0; j < 4; ++j) {
                const int iL = __shfl(idxv, 4 * j + q);
                lv[j] = *(const short8*)(leftb + iL * D + lq * 8);
            }
            #pragma unroll
            for (int j = 0; j < 4; ++j) {
                const int iR = __shfl(idxv, 32 + 4 * j + q);
                rv[j] = *(const short8*)(rightb + iR * D + lq * 8);
            }
            #pragma unroll
            for (int j = 0; j < 4; ++j) {
                short8 xb;
                #pragma unroll
                for (int e = 0; e < 8; ++e)
                    xb[e] = f2bf(bf2f(lv[j][e]) * bf2f(rv[j][e]));
                *(short8*)(xls + swz(4 * j + q, lq * 16)) = xb;
            }
        } else {
            // ---- f32 gather (fallback): whole-row float4 reads, burst ----
            float4 lv[8], rv[8];
            #pragma unroll
            for (int j = 0; j < 8; ++j) {
                const int eoff = 2 * j + half;
                const int iL = __shfl(idxv, eoff);
                const int iR = __shfl(idxv, 32 + eoff);
                lv[j] = *(const float4*)(left  + iL * D + l32 * 4);
                rv[j] = *(const float4*)(right + iR * D + l32 * 4);
            }
            #pragma unroll
            for (int j = 0; j < 8; ++j) {
                const int eoff = 2 * j + half;
                short4 xb;
                xb.x = f2bf(lv[j].x * rv[j].x);
                xb.y = f2bf(lv[j].y * rv[j].y);
                xb.z = f2bf(lv[j].z * rv[j].z);
                xb.w = f2bf(lv[j].w * rv[j].w);
                *(short4*)(xls + swz(eoff, l32 * 8)) = xb;
            }
        }

        // ---- MFMA: A and B share the same k-mapping (K-perm invariant) ----
        bf16x8 afr[4];
        #pragma unroll
        for (int kt = 0; kt < 4; ++kt)
            afr[kt] = *(const bf16x8*)(xls + swz(lm, kt * 64 + lg * 16));

        f32x4 acc[8];
        #pragma unroll
        for (int ct = 0; ct < 8; ++ct) acc[ct] = (f32x4){0.f, 0.f, 0.f, 0.f};

        #pragma unroll
        for (int kt = 0; kt < 4; ++kt)
            #pragma unroll
            for (int ct = 0; ct < 8; ++ct) {
                const bf16x8 bfr = *(const bf16x8*)(
                    w1t + swz(ct * 16 + lm, kt * 64 + lg * 16));
                acc[ct] = __builtin_amdgcn_mfma_f32_16x16x32_bf16(
                    afr[kt], bfr, acc[ct], 0, 0, 0);
            }

        // ---- bias + ReLU + dot(W2) + 16-lane reduce + sigmoid ----
        // C-frag layout (HW-measured): col = lane&15, row = (lane>>4)*4 + reg.
        float p0 = 0.f, p1 = 0.f, p2 = 0.f, p3 = 0.f;
        #pragma unroll
        for (int ct = 0; ct < 8; ++ct) {
            float h0 = fmaxf(acc[ct][0] + b1v[ct], 0.f);
            float h1 = fmaxf(acc[ct][1] + b1v[ct], 0.f);
            float h2 = fmaxf(acc[ct][2] + b1v[ct], 0.f);
            float h3 = fmaxf(acc[ct][3] + b1v[ct], 0.f);
            p0 = fmaf(h0, w2v[ct], p0);
            p1 = fmaf(h1, w2v[ct], p1);
            p2 = fmaf(h2, w2v[ct], p2);
            p3 = fmaf(h3, w2v[ct], p3);
        }
        #pragma unroll
        for (int s = 1; s < 16; s <<= 1) {
            p0 += __shfl_xor(p0, s);
            p1 += __shfl_xor(p1, s);
            p2 += __shfl_xor(p2, s);
            p3 += __shfl_xor(p3, s);
        }
        if (lm < 4) {
            const float pv = (lm & 2) ? ((lm & 1) ? p3 : p2)
                                      : ((lm & 1) ? p1 : p0);
            const int e = base + lg * 4 + lm;   // row = lg*4 + reg
            if (e < E) out[e] = 1.f / (1.f + __expf(-(pv + b2s)));
        }

        if (cn >= chunks) break;
        c = cn;
        idxv = idxv_n;
    }
}

extern "C" void kernel_launch(void* const* d_in, const int* in_sizes, int n_in,
                              void* d_out, int out_size, void* d_ws, size_t ws_size,
                              hipStream_t stream) {
    const float* left  = (const float*)d_in[0];
    const float* right = (const float*)d_in[1];
    const int*   pairs = (const int*)d_in[2];
    const float* W1    = (const float*)d_in[3];
    const float* b1    = (const float*)d_in[4];
    const float* W2    = (const float*)d_in[5];
    const float* b2    = (const float*)d_in[6];
    float* out = (float*)d_out;

    const int E = in_sizes[2] / 2;                 // pairs is [2][E]
    const int chunks = (E + CH - 1) / CH;
    int blocks = 512;                              // 2 blocks/CU * 256 CU
    const int need = (chunks + WAVES - 1) / WAVES;
    if (need < blocks) blocks = need;

    short* const wsp   = (short*)d_ws;             // [0,32KB): W1^T image
    short* const leftb = wsp + 16384;
    short* const rightb = leftb + in_sizes[0];

    const size_t need_ws = 32768 + (size_t)(in_sizes[0] + in_sizes[1]) * 2;

    prep_w1<<<64, 256, 0, stream>>>(W1, wsp);

    if (ws_size >= need_ws) {
        conv_bf16<<<2048, 256, 0, stream>>>(left,  leftb,  in_sizes[0] / 8);
        conv_bf16<<<2048, 256, 0, stream>>>(right, rightb, in_sizes[1] / 8);
        edge_decoder_kernel<1><<<blocks, BLK, 0, stream>>>(
            left, right, leftb, rightb, pairs, wsp, b1, W2, b2, out, E);
    } else {
        edge_decoder_kernel<0><<<blocks, BLK, 0, stream>>>(
            left, right, leftb, rightb, pairs, wsp, b1, W2, b2, out, E);
    }
}